// Round 1
// baseline (588.700 us; speedup 1.0000x reference)
//
#include <hip/hip_runtime.h>
#include <cmath>

// ---------------------------------------------------------------------------
// min_max_net: w' = weight with montn columns squared; y = x @ w'^T + bias;
// out[b] = (rand_u[b] < sigmoid(max_g min_{j in g} y[b, g*64+j])) ? 1 : 0
//
// Strategy: 2-way fp16 split GEMM on MFMA (fp32 accuracy at f16 MFMA rate/3).
// Splits written IN PLACE into d_in[0]/d_in[1] (harness restores pristine
// inputs before every launch; reference itself mutates weight in place).
// Row layout after convert: [2048 x fp16 hi | 2048 x fp16 lo] in the same 8KB.
// ---------------------------------------------------------------------------

typedef _Float16 f16x8 __attribute__((ext_vector_type(8)));
typedef float f32x4 __attribute__((ext_vector_type(4)));

__device__ __forceinline__ void async_load16(const void* gptr, void* lptr) {
  __builtin_amdgcn_global_load_lds(
      (const __attribute__((address_space(1))) void*)gptr,
      (__attribute__((address_space(3))) void*)lptr, 16, 0, 0);
}

// ---- kernel 1: column mask from montn_index --------------------------------
__global__ void build_mask(const int* __restrict__ idx, int* __restrict__ mask) {
  const int t = threadIdx.x;
  for (int k = t; k < 2048; k += 256) mask[k] = 0;
  __syncthreads();
  for (int j = t; j < 512; j += 256) mask[idx[j]] = 1;  // same-value races benign
}

// ---- kernel 2: in-place fp32 row -> [hi fp16 plane | lo fp16 plane] --------
// One block per row (2048 floats). LDS round-trip so all reads of the row
// complete before any thread overwrites it.
__global__ void convert_split(float* __restrict__ data,
                              const int* __restrict__ mask, int use_mask) {
  __shared__ float rowbuf[2048];
  const int r = blockIdx.x;
  const int t = threadIdx.x;  // 256
  float* rowp = data + (size_t)r * 2048;
  float4 v0 = ((const float4*)rowp)[t];
  float4 v1 = ((const float4*)rowp)[t + 256];
  ((float4*)rowbuf)[t] = v0;
  ((float4*)rowbuf)[t + 256] = v1;
  __syncthreads();

  const int k0 = t * 8;
  unsigned short hs[8], ls[8];
#pragma unroll
  for (int j = 0; j < 8; ++j) {
    float x = rowbuf[k0 + j];
    if (use_mask && mask[k0 + j]) x = x * x;
    _Float16 h = (_Float16)x;          // RTNE
    float res = x - (float)h;          // exact in fp32
    _Float16 l = (_Float16)res;
    hs[j] = __builtin_bit_cast(unsigned short, h);
    ls[j] = __builtin_bit_cast(unsigned short, l);
  }
  unsigned short* outp = (unsigned short*)rowp;
  uint4 Hv, Lv;
  Hv.x = (unsigned)hs[0] | ((unsigned)hs[1] << 16);
  Hv.y = (unsigned)hs[2] | ((unsigned)hs[3] << 16);
  Hv.z = (unsigned)hs[4] | ((unsigned)hs[5] << 16);
  Hv.w = (unsigned)hs[6] | ((unsigned)hs[7] << 16);
  Lv.x = (unsigned)ls[0] | ((unsigned)ls[1] << 16);
  Lv.y = (unsigned)ls[2] | ((unsigned)ls[3] << 16);
  Lv.z = (unsigned)ls[4] | ((unsigned)ls[5] << 16);
  Lv.w = (unsigned)ls[6] | ((unsigned)ls[7] << 16);
  *((uint4*)(outp + k0)) = Hv;            // hi plane: ushort [0, 2048)
  *((uint4*)(outp + 2048 + k0)) = Lv;     // lo plane: ushort [2048, 4096)
}

// ---- kernel 3: split-K' GEMM + fused bias/group-min ------------------------
// K' = 6144: seg0 = x_hi*w_hi, seg1 = x_hi*w_lo, seg2 = x_lo*w_hi.
// Block tile 128x128, 4 waves (2x2), each wave 64x64 via 4x4 MFMA 16x16x32.
// Wave's 64 cols == exactly one group of 64 -> plain store of group-min.
__global__ __launch_bounds__(256, 2) void gemm_minmax(
    const unsigned short* __restrict__ X, const unsigned short* __restrict__ W,
    const float* __restrict__ bias, float* __restrict__ gmins) {
  __shared__ unsigned short As[128 * 32];
  __shared__ unsigned short Bs[128 * 32];
  const int t = threadIdx.x;
  const int lane = t & 63;
  const int w = t >> 6;
  const int wm = w >> 1, wn = w & 1;
  const int m0 = blockIdx.y * 128;
  const int n0 = blockIdx.x * 128;

  // staging: slot s (of 512 per tile) -> row s>>2, 16B chunk s&3.
  // call0 covers slots [w*64 .. w*64+64), call1 slots [256 + w*64 ..).
  const int rS = w * 16 + (lane >> 2);     // 0..63
  const int cp = (lane & 3) * 8;           // ushort offset in row's 32-k chunk
  const size_t gA0 = (size_t)(m0 + rS) * 4096 + cp;
  const size_t gA1 = (size_t)(m0 + 64 + rS) * 4096 + cp;
  const size_t gB0 = (size_t)(n0 + rS) * 4096 + cp;
  const size_t gB1 = (size_t)(n0 + 64 + rS) * 4096 + cp;
  unsigned short* ldsA0 = As + w * 512;          // wave-uniform bases
  unsigned short* ldsA1 = As + 2048 + w * 512;
  unsigned short* ldsB0 = Bs + w * 512;
  unsigned short* ldsB1 = Bs + 2048 + w * 512;

  const int am = lane & 15, quad = lane >> 4;
  int aoff[4], boff[4];
#pragma unroll
  for (int i = 0; i < 4; ++i) {
    aoff[i] = (wm * 64 + i * 16 + am) * 32 + quad * 8;
    boff[i] = (wn * 64 + i * 16 + am) * 32 + quad * 8;
  }

  f32x4 acc[4][4];
#pragma unroll
  for (int i = 0; i < 4; ++i)
#pragma unroll
    for (int j = 0; j < 4; ++j) acc[i][j] = (f32x4){0.f, 0.f, 0.f, 0.f};

#pragma unroll 1
  for (int it = 0; it < 192; ++it) {
    const int kin = (it & 63) * 32;
    const int xoff = ((it >= 128) ? 2048 : 0) + kin;          // hi,hi,lo
    const int woff = ((it >= 64 && it < 128) ? 2048 : 0) + kin; // hi,lo,hi
    __syncthreads();  // previous iteration's LDS reads complete
    async_load16(X + gA0 + xoff, ldsA0);
    async_load16(X + gA1 + xoff, ldsA1);
    async_load16(W + gB0 + woff, ldsB0);
    async_load16(W + gB1 + woff, ldsB1);
    __syncthreads();  // staging complete (drains vmcnt)

    f16x8 av[4], bv[4];
#pragma unroll
    for (int i = 0; i < 4; ++i) av[i] = *(const f16x8*)(As + aoff[i]);
#pragma unroll
    for (int i = 0; i < 4; ++i) bv[i] = *(const f16x8*)(Bs + boff[i]);
#pragma unroll
    for (int mb = 0; mb < 4; ++mb)
#pragma unroll
      for (int nb = 0; nb < 4; ++nb)
        acc[mb][nb] = __builtin_amdgcn_mfma_f32_16x16x32_f16(
            av[mb], bv[nb], acc[mb][nb], 0, 0, 0);
  }

  // epilogue: bias + min over this wave's 64 cols (one group) per row
  float bv4[4];
#pragma unroll
  for (int nb = 0; nb < 4; ++nb) bv4[nb] = bias[n0 + wn * 64 + nb * 16 + am];
  const int grp = (n0 >> 6) + wn;
#pragma unroll
  for (int mb = 0; mb < 4; ++mb) {
#pragma unroll
    for (int reg = 0; reg < 4; ++reg) {
      float v = fminf(fminf(acc[mb][0][reg] + bv4[0], acc[mb][1][reg] + bv4[1]),
                      fminf(acc[mb][2][reg] + bv4[2], acc[mb][3][reg] + bv4[3]));
      v = fminf(v, __shfl_xor(v, 1, 64));
      v = fminf(v, __shfl_xor(v, 2, 64));
      v = fminf(v, __shfl_xor(v, 4, 64));
      v = fminf(v, __shfl_xor(v, 8, 64));  // min across the 16 cols per quad
      if (am == 0) {
        const int row = m0 + wm * 64 + mb * 16 + quad * 4 + reg;
        gmins[(size_t)row * 64 + grp] = v;
      }
    }
  }
}

// ---- kernel 4: max over groups -> sigmoid -> Bernoulli ---------------------
__global__ void finalize(const float* __restrict__ gmins,
                         const float* __restrict__ rand_u,
                         float* __restrict__ out) {
  const int wv = threadIdx.x >> 6, lane = threadIdx.x & 63;
  const int row = blockIdx.x * 4 + wv;
  float v = gmins[(size_t)row * 64 + lane];
  v = fmaxf(v, __shfl_xor(v, 1, 64));
  v = fmaxf(v, __shfl_xor(v, 2, 64));
  v = fmaxf(v, __shfl_xor(v, 4, 64));
  v = fmaxf(v, __shfl_xor(v, 8, 64));
  v = fmaxf(v, __shfl_xor(v, 16, 64));
  v = fmaxf(v, __shfl_xor(v, 32, 64));
  if (lane == 0) {
    const float s = 1.0f / (1.0f + expf(-v));
    out[row] = (rand_u[row] < s) ? 1.0f : 0.0f;
  }
}

extern "C" void kernel_launch(void* const* d_in, const int* in_sizes, int n_in,
                              void* d_out, int out_size, void* d_ws, size_t ws_size,
                              hipStream_t stream) {
  float* x = (float*)d_in[0];           // [8192, 2048] fp32 (mutated in place)
  float* weight = (float*)d_in[1];      // [4096, 2048] fp32 (mutated in place)
  const float* bias = (const float*)d_in[2];
  const float* rand_u = (const float*)d_in[3];
  const int* montn = (const int*)d_in[4];
  float* out = (float*)d_out;

  int* mask = (int*)d_ws;                            // 2048 ints = 8 KB
  float* gmins = (float*)((char*)d_ws + 8192);       // 8192*64 floats = 2 MB

  build_mask<<<1, 256, 0, stream>>>(montn, mask);
  convert_split<<<8192, 256, 0, stream>>>(x, mask, 0);
  convert_split<<<4096, 256, 0, stream>>>(weight, mask, 1);
  gemm_minmax<<<dim3(32, 64), 256, 0, stream>>>(
      (const unsigned short*)x, (const unsigned short*)weight, bias, gmins);
  finalize<<<2048, 256, 0, stream>>>(gmins, rand_u, out);
}

// Round 2
// 560.624 us; speedup vs baseline: 1.0501x; 1.0501x over previous
//
#include <hip/hip_runtime.h>
#include <cmath>

// ---------------------------------------------------------------------------
// min_max_net: w' = weight with montn columns squared; y = x @ w'^T + bias;
// out[b] = (rand_u[b] < sigmoid(max_g min_{j in g} y[b, g*64+j])) ? 1 : 0
//
// R2: BK=64 (32 MFMA per barrier pair, 32KB LDS) + XOR-swizzled LDS chunks
// to kill the 8-way ds_read_b128 bank conflicts observed in R1 (5e7 cycles).
// fp16 2-way split GEMM (hi*hi + hi*lo + lo*hi), splits written in place.
// ---------------------------------------------------------------------------

typedef _Float16 f16x8 __attribute__((ext_vector_type(8)));
typedef float f32x4 __attribute__((ext_vector_type(4)));

__device__ __forceinline__ void async_load16(const void* gptr, void* lptr) {
  __builtin_amdgcn_global_load_lds(
      (const __attribute__((address_space(1))) void*)gptr,
      (__attribute__((address_space(3))) void*)lptr, 16, 0, 0);
}

// ---- kernel 1: column mask from montn_index --------------------------------
__global__ void build_mask(const int* __restrict__ idx, int* __restrict__ mask) {
  const int t = threadIdx.x;
  for (int k = t; k < 2048; k += 256) mask[k] = 0;
  __syncthreads();
  for (int j = t; j < 512; j += 256) mask[idx[j]] = 1;  // same-value races benign
}

// ---- kernel 2: in-place fp32 row -> [hi fp16 plane | lo fp16 plane] --------
// blocks [0,8192) convert x rows (no mask); [8192,12288) convert weight rows.
__global__ void convert_split(float* __restrict__ x, float* __restrict__ wgt,
                              const int* __restrict__ mask) {
  __shared__ float rowbuf[2048];
  const int b = blockIdx.x;
  const int t = threadIdx.x;  // 256
  const int use_mask = (b >= 8192) ? 1 : 0;
  float* rowp = use_mask ? (wgt + (size_t)(b - 8192) * 2048)
                         : (x + (size_t)b * 2048);
  float4 v0 = ((const float4*)rowp)[t];
  float4 v1 = ((const float4*)rowp)[t + 256];
  ((float4*)rowbuf)[t] = v0;
  ((float4*)rowbuf)[t + 256] = v1;
  __syncthreads();

  const int k0 = t * 8;
  unsigned short hs[8], ls[8];
#pragma unroll
  for (int j = 0; j < 8; ++j) {
    float v = rowbuf[k0 + j];
    if (use_mask && mask[k0 + j]) v = v * v;
    _Float16 h = (_Float16)v;          // RTNE
    float res = v - (float)h;          // exact in fp32
    _Float16 l = (_Float16)res;
    hs[j] = __builtin_bit_cast(unsigned short, h);
    ls[j] = __builtin_bit_cast(unsigned short, l);
  }
  unsigned short* outp = (unsigned short*)rowp;
  uint4 Hv, Lv;
  Hv.x = (unsigned)hs[0] | ((unsigned)hs[1] << 16);
  Hv.y = (unsigned)hs[2] | ((unsigned)hs[3] << 16);
  Hv.z = (unsigned)hs[4] | ((unsigned)hs[5] << 16);
  Hv.w = (unsigned)hs[6] | ((unsigned)hs[7] << 16);
  Lv.x = (unsigned)ls[0] | ((unsigned)ls[1] << 16);
  Lv.y = (unsigned)ls[2] | ((unsigned)ls[3] << 16);
  Lv.z = (unsigned)ls[4] | ((unsigned)ls[5] << 16);
  Lv.w = (unsigned)ls[6] | ((unsigned)ls[7] << 16);
  *((uint4*)(outp + k0)) = Hv;            // hi plane: ushort [0, 2048)
  *((uint4*)(outp + 2048 + k0)) = Lv;     // lo plane: ushort [2048, 4096)
}

// ---- kernel 3: split-K' GEMM + fused bias/group-min ------------------------
// K' = 6144 over 96 iters of BK=64: it<32 x_hi*w_hi, 32..63 x_hi*w_lo,
// 64..95 x_lo*w_hi. Block tile 128x128, 4 waves (2x2), wave 64x64 via
// 4x4 MFMA 16x16x32 f16, two sub-k per iter (32 MFMA per barrier pair).
// LDS layout: row-major [128][64] ushort; 16B chunk c stored at c ^ (row&7)
// so fragment ds_read_b128 spreads over all 32 banks (R1: 8-way conflicts).
__global__ __launch_bounds__(256, 2) void gemm_minmax(
    const unsigned short* __restrict__ X, const unsigned short* __restrict__ W,
    const float* __restrict__ bias, float* __restrict__ gmins) {
  __shared__ unsigned short As[128 * 64];
  __shared__ unsigned short Bs[128 * 64];
  const int t = threadIdx.x;
  const int lane = t & 63;
  const int w = t >> 6;
  const int wm = w >> 1, wn = w & 1;
  const int m0 = blockIdx.y * 128;
  const int n0 = blockIdx.x * 128;

  // --- staging geometry (4 calls per matrix per iter) ---
  // call c: wave w covers LDS bytes [c*4096 + w*1024, +1024); lane l writes
  // 16B at +l*16 -> row c*32 + w*8 + (l>>3), stored-chunk l&7.
  // Stored-chunk s holds global chunk s ^ (row&7); row&7 == (l>>3)&7 here,
  // so lane's global chunk = (l&7) ^ ((l>>3)&7)  (lane-constant).
  const int rowBase = w * 8 + (lane >> 3);
  const int gchunk = ((lane & 7) ^ ((lane >> 3) & 7)) * 8;  // ushort offset
  size_t sA[4], sB[4];
#pragma unroll
  for (int c = 0; c < 4; ++c) {
    sA[c] = (size_t)(m0 + c * 32 + rowBase) * 4096 + gchunk;
    sB[c] = (size_t)(n0 + c * 32 + rowBase) * 4096 + gchunk;
  }
  unsigned short* ldsA[4];
  unsigned short* ldsB[4];
#pragma unroll
  for (int c = 0; c < 4; ++c) {
    ldsA[c] = As + c * 2048 + w * 512;  // wave-uniform bases (ushort units)
    ldsB[c] = Bs + c * 2048 + w * 512;
  }

  // --- fragment geometry ---
  const int am = lane & 15, quad = lane >> 4;
  // A row = wm*64 + i*16 + am  (row&7 == am&7); same for B with wn.
  int arow[4], brow[4];
#pragma unroll
  for (int i = 0; i < 4; ++i) {
    arow[i] = (wm * 64 + i * 16 + am) * 64;
    brow[i] = (wn * 64 + i * 16 + am) * 64;
  }
  int swz[2];
#pragma unroll
  for (int h = 0; h < 2; ++h) swz[h] = (((h << 2) + quad) ^ (am & 7)) * 8;

  f32x4 acc[4][4];
#pragma unroll
  for (int i = 0; i < 4; ++i)
#pragma unroll
    for (int j = 0; j < 4; ++j) acc[i][j] = (f32x4){0.f, 0.f, 0.f, 0.f};

#pragma unroll 1
  for (int it = 0; it < 96; ++it) {
    const int kin = (it & 31) * 64;
    const int xoff = ((it >= 64) ? 2048 : 0) + kin;               // hi,hi,lo
    const int woff = ((it >= 32 && it < 64) ? 2048 : 0) + kin;    // hi,lo,hi
    __syncthreads();  // previous iteration's LDS reads complete
#pragma unroll
    for (int c = 0; c < 4; ++c) {
      async_load16(X + sA[c] + xoff, ldsA[c]);
      async_load16(W + sB[c] + woff, ldsB[c]);
    }
    __syncthreads();  // staging complete (drains vmcnt)

#pragma unroll
    for (int h = 0; h < 2; ++h) {
      f16x8 av[4], bv[4];
#pragma unroll
      for (int i = 0; i < 4; ++i) av[i] = *(const f16x8*)(As + arow[i] + swz[h]);
#pragma unroll
      for (int i = 0; i < 4; ++i) bv[i] = *(const f16x8*)(Bs + brow[i] + swz[h]);
#pragma unroll
      for (int mb = 0; mb < 4; ++mb)
#pragma unroll
        for (int nb = 0; nb < 4; ++nb)
          acc[mb][nb] = __builtin_amdgcn_mfma_f32_16x16x32_f16(
              av[mb], bv[nb], acc[mb][nb], 0, 0, 0);
    }
  }

  // epilogue: bias + min over this wave's 64 cols (one group) per row
  float bv4[4];
#pragma unroll
  for (int nb = 0; nb < 4; ++nb) bv4[nb] = bias[n0 + wn * 64 + nb * 16 + am];
  const int grp = (n0 >> 6) + wn;
#pragma unroll
  for (int mb = 0; mb < 4; ++mb) {
#pragma unroll
    for (int reg = 0; reg < 4; ++reg) {
      float v = fminf(fminf(acc[mb][0][reg] + bv4[0], acc[mb][1][reg] + bv4[1]),
                      fminf(acc[mb][2][reg] + bv4[2], acc[mb][3][reg] + bv4[3]));
      v = fminf(v, __shfl_xor(v, 1, 64));
      v = fminf(v, __shfl_xor(v, 2, 64));
      v = fminf(v, __shfl_xor(v, 4, 64));
      v = fminf(v, __shfl_xor(v, 8, 64));  // min across the 16 cols per quad
      if (am == 0) {
        const int row = m0 + wm * 64 + mb * 16 + quad * 4 + reg;
        gmins[(size_t)row * 64 + grp] = v;
      }
    }
  }
}

// ---- kernel 4: max over groups -> sigmoid -> Bernoulli ---------------------
__global__ void finalize(const float* __restrict__ gmins,
                         const float* __restrict__ rand_u,
                         float* __restrict__ out) {
  const int wv = threadIdx.x >> 6, lane = threadIdx.x & 63;
  const int row = blockIdx.x * 4 + wv;
  float v = gmins[(size_t)row * 64 + lane];
  v = fmaxf(v, __shfl_xor(v, 1, 64));
  v = fmaxf(v, __shfl_xor(v, 2, 64));
  v = fmaxf(v, __shfl_xor(v, 4, 64));
  v = fmaxf(v, __shfl_xor(v, 8, 64));
  v = fmaxf(v, __shfl_xor(v, 16, 64));
  v = fmaxf(v, __shfl_xor(v, 32, 64));
  if (lane == 0) {
    const float s = 1.0f / (1.0f + expf(-v));
    out[row] = (rand_u[row] < s) ? 1.0f : 0.0f;
  }
}

extern "C" void kernel_launch(void* const* d_in, const int* in_sizes, int n_in,
                              void* d_out, int out_size, void* d_ws, size_t ws_size,
                              hipStream_t stream) {
  float* x = (float*)d_in[0];           // [8192, 2048] fp32 (mutated in place)
  float* weight = (float*)d_in[1];      // [4096, 2048] fp32 (mutated in place)
  const float* bias = (const float*)d_in[2];
  const float* rand_u = (const float*)d_in[3];
  const int* montn = (const int*)d_in[4];
  float* out = (float*)d_out;

  int* mask = (int*)d_ws;                            // 2048 ints = 8 KB
  float* gmins = (float*)((char*)d_ws + 8192);       // 8192*64 floats = 2 MB

  build_mask<<<1, 256, 0, stream>>>(montn, mask);
  convert_split<<<12288, 256, 0, stream>>>(x, weight, mask);
  gemm_minmax<<<dim3(32, 64), 256, 0, stream>>>(
      (const unsigned short*)x, (const unsigned short*)weight, bias, gmins);
  finalize<<<2048, 256, 0, stream>>>(gmins, rand_u, out);
}

// Round 3
// 355.092 us; speedup vs baseline: 1.6579x; 1.5788x over previous
//
#include <hip/hip_runtime.h>
#include <cmath>

// ---------------------------------------------------------------------------
// min_max_net: w' = weight with montn columns squared; y = x @ w'^T + bias;
// out[b] = (rand_u[b] < sigmoid(max_g min_{j in g} y[b, g*64+j])) ? 1 : 0
//
// R3: binary output => probabilistic precision. Pass 1 = fp16 hi*hi GEMM only
// (K=2048, 1/3 the MFMA work of R2). Error sigma ~3.6e-4 (CLT over 2048
// roundings); margin EPS=4e-3 (~11 sigma). Rows where rand_u falls inside
// [sig(v-EPS), sig(v+EPS)] (~16 of 8192) get an exact fp32 recompute of the
// full y-row from the hi+lo planes (exact fp32 reconstruction).
// GEMM structure = R2's (bit-verified): BK=64, XOR-swizzled LDS, 0 conflicts.
// ---------------------------------------------------------------------------

typedef _Float16 f16x8 __attribute__((ext_vector_type(8)));
typedef float f32x4 __attribute__((ext_vector_type(4)));

__device__ __forceinline__ void async_load16(const void* gptr, void* lptr) {
  __builtin_amdgcn_global_load_lds(
      (const __attribute__((address_space(1))) void*)gptr,
      (__attribute__((address_space(3))) void*)lptr, 16, 0, 0);
}

__device__ __forceinline__ float us2f(unsigned short u) {
  return (float)__builtin_bit_cast(_Float16, u);
}

#define MARGIN_EPS 4e-3f

// ---- kernel 1: column mask + zero count/slotmax ----------------------------
__global__ void build_mask(const int* __restrict__ idx, int* __restrict__ mask,
                           int* __restrict__ count, unsigned* __restrict__ slotmax) {
  const int t = threadIdx.x;
  for (int k = t; k < 2048; k += 256) mask[k] = 0;
  for (int k = t; k < 8192; k += 256) slotmax[k] = 0u;  // < any finite key
  if (t == 0) *count = 0;
  __syncthreads();
  for (int j = t; j < 512; j += 256) mask[idx[j]] = 1;  // same-value races benign
}

// ---- kernel 2: in-place fp32 row -> [hi fp16 plane | lo fp16 plane] --------
// blocks [0,8192) convert x rows (no mask); [8192,12288) convert weight rows.
__global__ void convert_split(float* __restrict__ x, float* __restrict__ wgt,
                              const int* __restrict__ mask) {
  __shared__ float rowbuf[2048];
  const int b = blockIdx.x;
  const int t = threadIdx.x;  // 256
  const int use_mask = (b >= 8192) ? 1 : 0;
  float* rowp = use_mask ? (wgt + (size_t)(b - 8192) * 2048)
                         : (x + (size_t)b * 2048);
  float4 v0 = ((const float4*)rowp)[t];
  float4 v1 = ((const float4*)rowp)[t + 256];
  ((float4*)rowbuf)[t] = v0;
  ((float4*)rowbuf)[t + 256] = v1;
  __syncthreads();

  const int k0 = t * 8;
  unsigned short hs[8], ls[8];
#pragma unroll
  for (int j = 0; j < 8; ++j) {
    float v = rowbuf[k0 + j];
    if (use_mask && mask[k0 + j]) v = v * v;
    _Float16 h = (_Float16)v;          // RTNE
    float res = v - (float)h;          // exact in fp32
    _Float16 l = (_Float16)res;
    hs[j] = __builtin_bit_cast(unsigned short, h);
    ls[j] = __builtin_bit_cast(unsigned short, l);
  }
  unsigned short* outp = (unsigned short*)rowp;
  uint4 Hv, Lv;
  Hv.x = (unsigned)hs[0] | ((unsigned)hs[1] << 16);
  Hv.y = (unsigned)hs[2] | ((unsigned)hs[3] << 16);
  Hv.z = (unsigned)hs[4] | ((unsigned)hs[5] << 16);
  Hv.w = (unsigned)hs[6] | ((unsigned)hs[7] << 16);
  Lv.x = (unsigned)ls[0] | ((unsigned)ls[1] << 16);
  Lv.y = (unsigned)ls[2] | ((unsigned)ls[3] << 16);
  Lv.z = (unsigned)ls[4] | ((unsigned)ls[5] << 16);
  Lv.w = (unsigned)ls[6] | ((unsigned)ls[7] << 16);
  *((uint4*)(outp + k0)) = Hv;            // hi plane: ushort [0, 2048)
  *((uint4*)(outp + 2048 + k0)) = Lv;     // lo plane: ushort [2048, 4096)
}

// ---- kernel 3: hi*hi GEMM + fused bias/group-min (approx, err < 4e-3) ------
// K = 2048 over 32 iters of BK=64. Block 128x128, 4 waves (2x2), wave 64x64
// via 4x4 MFMA 16x16x32 f16. XOR-swizzled LDS chunks (R2: zero conflicts).
__global__ __launch_bounds__(256, 2) void gemm_minmax(
    const unsigned short* __restrict__ X, const unsigned short* __restrict__ W,
    const float* __restrict__ bias, float* __restrict__ gmins) {
  __shared__ unsigned short As[128 * 64];
  __shared__ unsigned short Bs[128 * 64];
  const int t = threadIdx.x;
  const int lane = t & 63;
  const int w = t >> 6;
  const int wm = w >> 1, wn = w & 1;
  const int m0 = blockIdx.y * 128;
  const int n0 = blockIdx.x * 128;

  const int rowBase = w * 8 + (lane >> 3);
  const int gchunk = ((lane & 7) ^ ((lane >> 3) & 7)) * 8;  // ushort offset
  size_t sA[4], sB[4];
#pragma unroll
  for (int c = 0; c < 4; ++c) {
    sA[c] = (size_t)(m0 + c * 32 + rowBase) * 4096 + gchunk;
    sB[c] = (size_t)(n0 + c * 32 + rowBase) * 4096 + gchunk;
  }
  unsigned short* ldsA[4];
  unsigned short* ldsB[4];
#pragma unroll
  for (int c = 0; c < 4; ++c) {
    ldsA[c] = As + c * 2048 + w * 512;  // wave-uniform bases (ushort units)
    ldsB[c] = Bs + c * 2048 + w * 512;
  }

  const int am = lane & 15, quad = lane >> 4;
  int arow[4], brow[4];
#pragma unroll
  for (int i = 0; i < 4; ++i) {
    arow[i] = (wm * 64 + i * 16 + am) * 64;
    brow[i] = (wn * 64 + i * 16 + am) * 64;
  }
  int swz[2];
#pragma unroll
  for (int h = 0; h < 2; ++h) swz[h] = (((h << 2) + quad) ^ (am & 7)) * 8;

  f32x4 acc[4][4];
#pragma unroll
  for (int i = 0; i < 4; ++i)
#pragma unroll
    for (int j = 0; j < 4; ++j) acc[i][j] = (f32x4){0.f, 0.f, 0.f, 0.f};

#pragma unroll 1
  for (int it = 0; it < 32; ++it) {
    const int kin = it * 64;
    __syncthreads();  // previous iteration's LDS reads complete
#pragma unroll
    for (int c = 0; c < 4; ++c) {
      async_load16(X + sA[c] + kin, ldsA[c]);
      async_load16(W + sB[c] + kin, ldsB[c]);
    }
    __syncthreads();  // staging complete (drains vmcnt)

#pragma unroll
    for (int h = 0; h < 2; ++h) {
      f16x8 av[4], bv[4];
#pragma unroll
      for (int i = 0; i < 4; ++i) av[i] = *(const f16x8*)(As + arow[i] + swz[h]);
#pragma unroll
      for (int i = 0; i < 4; ++i) bv[i] = *(const f16x8*)(Bs + brow[i] + swz[h]);
#pragma unroll
      for (int mb = 0; mb < 4; ++mb)
#pragma unroll
        for (int nb = 0; nb < 4; ++nb)
          acc[mb][nb] = __builtin_amdgcn_mfma_f32_16x16x32_f16(
              av[mb], bv[nb], acc[mb][nb], 0, 0, 0);
    }
  }

  float bv4[4];
#pragma unroll
  for (int nb = 0; nb < 4; ++nb) bv4[nb] = bias[n0 + wn * 64 + nb * 16 + am];
  const int grp = (n0 >> 6) + wn;
#pragma unroll
  for (int mb = 0; mb < 4; ++mb) {
#pragma unroll
    for (int reg = 0; reg < 4; ++reg) {
      float v = fminf(fminf(acc[mb][0][reg] + bv4[0], acc[mb][1][reg] + bv4[1]),
                      fminf(acc[mb][2][reg] + bv4[2], acc[mb][3][reg] + bv4[3]));
      v = fminf(v, __shfl_xor(v, 1, 64));
      v = fminf(v, __shfl_xor(v, 2, 64));
      v = fminf(v, __shfl_xor(v, 4, 64));
      v = fminf(v, __shfl_xor(v, 8, 64));
      if (am == 0) {
        const int row = m0 + wm * 64 + mb * 16 + quad * 4 + reg;
        gmins[(size_t)row * 64 + grp] = v;
      }
    }
  }
}

// ---- kernel 4: max over groups -> margin test ------------------------------
__global__ void finalize_margin(const float* __restrict__ gmins,
                                const float* __restrict__ rand_u,
                                float* __restrict__ out,
                                int* __restrict__ count, int* __restrict__ undec) {
  const int wv = threadIdx.x >> 6, lane = threadIdx.x & 63;
  const int row = blockIdx.x * 4 + wv;
  float v = gmins[(size_t)row * 64 + lane];
  v = fmaxf(v, __shfl_xor(v, 1, 64));
  v = fmaxf(v, __shfl_xor(v, 2, 64));
  v = fmaxf(v, __shfl_xor(v, 4, 64));
  v = fmaxf(v, __shfl_xor(v, 8, 64));
  v = fmaxf(v, __shfl_xor(v, 16, 64));
  v = fmaxf(v, __shfl_xor(v, 32, 64));
  if (lane == 0) {
    const float u = rand_u[row];
    const float slo = 1.0f / (1.0f + expf(-(v - MARGIN_EPS)));
    const float shi = 1.0f / (1.0f + expf(-(v + MARGIN_EPS)));
    if (u < slo) {
      out[row] = 1.0f;         // true sigmoid >= slo > u
    } else if (u >= shi) {
      out[row] = 0.0f;         // true sigmoid <= shi <= u
    } else {
      const int i = atomicAdd(count, 1);
      undec[i] = row;          // decide kernel writes out[row]
    }
  }
}

// ---- kernel 5: exact fp32 recompute of undecided rows ----------------------
// grid (64 groups, 64 slot-strides) x 256 thr. Block (g, s): exact group-min
// of row undec[s] over cols [g*64, g*64+64), atomicMax into slotmax[s]
// (order-preserving uint encoding -> max over groups).
__global__ __launch_bounds__(256) void recompute_rows(
    const unsigned short* __restrict__ X, const unsigned short* __restrict__ W,
    const float* __restrict__ bias, const int* __restrict__ count,
    const int* __restrict__ undec, unsigned* __restrict__ slotmax) {
  __shared__ float xf[2048];
  __shared__ float part[256];
  const int g = blockIdx.x;
  const int t = threadIdx.x;
  const int n = *count;
  for (int s = blockIdx.y; s < n; s += gridDim.y) {
    const int row = undec[s];
    {  // x row: hi+lo -> exact fp32 in LDS
      const unsigned short* xr = X + (size_t)row * 4096;
      const int k0 = t * 8;
      uint4 hv = *(const uint4*)(xr + k0);
      uint4 lv = *(const uint4*)(xr + 2048 + k0);
      const unsigned* hw = (const unsigned*)&hv;
      const unsigned* lw = (const unsigned*)&lv;
#pragma unroll
      for (int j = 0; j < 4; ++j) {
        xf[k0 + 2 * j] = us2f((unsigned short)(hw[j] & 0xFFFF)) +
                         us2f((unsigned short)(lw[j] & 0xFFFF));
        xf[k0 + 2 * j + 1] = us2f((unsigned short)(hw[j] >> 16)) +
                             us2f((unsigned short)(lw[j] >> 16));
      }
    }
    __syncthreads();
    const int c = g * 64 + (t >> 2);   // column
    const int q = t & 3;               // k-quarter
    const unsigned short* wr = W + (size_t)c * 4096 + q * 512;
    float acc = 0.f;
    for (int i = 0; i < 512; i += 8) {
      uint4 hv = *(const uint4*)(wr + i);
      uint4 lv = *(const uint4*)(wr + 2048 + i);
      const unsigned* hw = (const unsigned*)&hv;
      const unsigned* lw = (const unsigned*)&lv;
#pragma unroll
      for (int j = 0; j < 4; ++j) {
        float w0 = us2f((unsigned short)(hw[j] & 0xFFFF)) +
                   us2f((unsigned short)(lw[j] & 0xFFFF));
        float w1 = us2f((unsigned short)(hw[j] >> 16)) +
                   us2f((unsigned short)(lw[j] >> 16));
        acc = fmaf(xf[q * 512 + i + 2 * j], w0, acc);
        acc = fmaf(xf[q * 512 + i + 2 * j + 1], w1, acc);
      }
    }
    part[t] = acc;
    __syncthreads();
    if (t < 64) {
      float y = part[t * 4] + part[t * 4 + 1] + part[t * 4 + 2] + part[t * 4 + 3]
                + bias[g * 64 + t];
      y = fminf(y, __shfl_xor(y, 1, 64));
      y = fminf(y, __shfl_xor(y, 2, 64));
      y = fminf(y, __shfl_xor(y, 4, 64));
      y = fminf(y, __shfl_xor(y, 8, 64));
      y = fminf(y, __shfl_xor(y, 16, 64));
      y = fminf(y, __shfl_xor(y, 32, 64));
      if (t == 0) {
        const unsigned u = __float_as_uint(y);
        const unsigned key = (u & 0x80000000u) ? ~u : (u | 0x80000000u);
        atomicMax(slotmax + s, key);
      }
    }
    __syncthreads();  // LDS reused next slot iteration
  }
}

// ---- kernel 6: final decision for undecided rows ---------------------------
__global__ void decide(const unsigned* __restrict__ slotmax,
                       const int* __restrict__ undec, const int* __restrict__ count,
                       const float* __restrict__ rand_u, float* __restrict__ out) {
  const int n = *count;
  for (int s = blockIdx.x * blockDim.x + threadIdx.x; s < n;
       s += gridDim.x * blockDim.x) {
    const unsigned key = slotmax[s];
    const unsigned u = (key & 0x80000000u) ? (key & 0x7FFFFFFFu) : ~key;
    const float v = __uint_as_float(u);
    const int row = undec[s];
    const float sg = 1.0f / (1.0f + expf(-v));
    out[row] = (rand_u[row] < sg) ? 1.0f : 0.0f;
  }
}

extern "C" void kernel_launch(void* const* d_in, const int* in_sizes, int n_in,
                              void* d_out, int out_size, void* d_ws, size_t ws_size,
                              hipStream_t stream) {
  float* x = (float*)d_in[0];           // [8192, 2048] fp32 (mutated in place)
  float* weight = (float*)d_in[1];      // [4096, 2048] fp32 (mutated in place)
  const float* bias = (const float*)d_in[2];
  const float* rand_u = (const float*)d_in[3];
  const int* montn = (const int*)d_in[4];
  float* out = (float*)d_out;

  char* ws = (char*)d_ws;
  int* mask = (int*)ws;                          // 8 KB
  int* count = (int*)(ws + 8192);                // 4 B
  int* undec = (int*)(ws + 8448);                // 32 KB (8192 slots)
  unsigned* slotmax = (unsigned*)(ws + 41216);   // 32 KB (8192 slots)
  float* gmins = (float*)(ws + 131072);          // 2 MB

  build_mask<<<1, 256, 0, stream>>>(montn, mask, count, slotmax);
  convert_split<<<12288, 256, 0, stream>>>(x, weight, mask);
  gemm_minmax<<<dim3(32, 64), 256, 0, stream>>>(
      (const unsigned short*)x, (const unsigned short*)weight, bias, gmins);
  finalize_margin<<<2048, 256, 0, stream>>>(gmins, rand_u, out, count, undec);
  recompute_rows<<<dim3(64, 64), 256, 0, stream>>>(
      (const unsigned short*)x, (const unsigned short*)weight, bias,
      count, undec, slotmax);
  decide<<<32, 256, 0, stream>>>(slotmax, undec, count, rand_u, out);
}

// Round 4
// 308.725 us; speedup vs baseline: 1.9069x; 1.1502x over previous
//
#include <hip/hip_runtime.h>
#include <cmath>

// ---------------------------------------------------------------------------
// min_max_net: w' = weight with montn columns squared; y = x @ w'^T + bias;
// out[b] = (rand_u[b] < sigmoid(max_g min_{j in g} y[b, g*64+j])) ? 1 : 0
//
// R4: (a) GEMM wave tile 64x128 (block 128x256) to cut LDS-read/FLOP 25% and
// amortize barrier drain; (b) wave-private in-register convert (no LDS, no
// barrier, fully coalesced); (c) recompute reads W once (LDS-staged fp32
// chunks, 96-slot ybuf + atomicAdd partials).
// fp16 hi*hi GEMM (sigma ~3.6e-4), margin 4e-3, exact fp32 recompute of
// undecided rows (~16 expected, cap 96, P(overflow) ~ 1e-20).
// ---------------------------------------------------------------------------

typedef _Float16 f16x8 __attribute__((ext_vector_type(8)));
typedef float f32x4 __attribute__((ext_vector_type(4)));

#define MARGIN_EPS 4e-3f
#define MAX_UNDEC 96

__device__ __forceinline__ void async_load16(const void* gptr, void* lptr) {
  __builtin_amdgcn_global_load_lds(
      (const __attribute__((address_space(1))) void*)gptr,
      (__attribute__((address_space(3))) void*)lptr, 16, 0, 0);
}

__device__ __forceinline__ float us2f(unsigned short u) {
  return (float)__builtin_bit_cast(_Float16, u);
}

// ---- kernel 1: 64-word column bitmask + count=0 ----------------------------
__global__ void build_mask(const int* __restrict__ idx,
                           unsigned* __restrict__ mask32, int* __restrict__ count) {
  const int t = threadIdx.x;
  if (t < 64) mask32[t] = 0u;
  if (t == 0) *count = 0;
  __syncthreads();
  for (int j = t; j < 512; j += 256) {
    const int c = idx[j];
    atomicOr(&mask32[c >> 5], 1u << (c & 31));
  }
}

// ---- kernel 2: in-place fp32 row -> [hi fp16 | lo fp16], 1 wave per row ----
// In-wave ordering: all 8 loads precede any store (aliasing keeps order).
// Lane l owns floats {4l+256j : j<8}; coalesced float4 loads, uint2 stores.
__global__ void convert_split(float* __restrict__ x, float* __restrict__ wgt,
                              const unsigned* __restrict__ mask32) {
  const int t = threadIdx.x, l = t & 63, w = t >> 6;
  const int r = blockIdx.x * 4 + w;
  const int use_mask = (r >= 8192) ? 1 : 0;
  float* rowp = use_mask ? (wgt + (size_t)(r - 8192) * 2048)
                         : (x + (size_t)r * 2048);
  float4 v[8];
#pragma unroll
  for (int j = 0; j < 8; ++j) v[j] = ((const float4*)rowp)[l + 64 * j];
  unsigned mw[8];
#pragma unroll
  for (int j = 0; j < 8; ++j)
    mw[j] = use_mask ? mask32[(l >> 3) + 8 * j] : 0u;

  unsigned short* up = (unsigned short*)rowp;
#pragma unroll
  for (int j = 0; j < 8; ++j) {
    unsigned short hs[4], ls[4];
    const float* fv = (const float*)&v[j];
#pragma unroll
    for (int c = 0; c < 4; ++c) {
      float f = fv[c];
      if ((mw[j] >> (4 * (l & 7) + c)) & 1u) f = f * f;
      _Float16 h = (_Float16)f;          // RTNE
      float res = f - (float)h;          // exact in fp32
      _Float16 lo = (_Float16)res;
      hs[c] = __builtin_bit_cast(unsigned short, h);
      ls[c] = __builtin_bit_cast(unsigned short, lo);
    }
    uint2 H, L;
    H.x = (unsigned)hs[0] | ((unsigned)hs[1] << 16);
    H.y = (unsigned)hs[2] | ((unsigned)hs[3] << 16);
    L.x = (unsigned)ls[0] | ((unsigned)ls[1] << 16);
    L.y = (unsigned)ls[2] | ((unsigned)ls[3] << 16);
    *((uint2*)(up + 4 * l + 256 * j)) = H;           // hi plane [0,2048)
    *((uint2*)(up + 2048 + 4 * l + 256 * j)) = L;    // lo plane [2048,4096)
  }
}

// ---- kernel 3: hi*hi GEMM + fused bias/group-min ---------------------------
// Block tile 128x256, BK=64, 4 waves (2x2), wave tile 64x128 via 4x8 MFMA
// 16x16x32 f16. XOR-swizzled LDS chunks (verified zero conflicts R2/R3).
__global__ __launch_bounds__(256, 2) void gemm_minmax(
    const unsigned short* __restrict__ X, const unsigned short* __restrict__ W,
    const float* __restrict__ bias, float* __restrict__ gmins) {
  __shared__ unsigned short As[128 * 64];   // 16 KB
  __shared__ unsigned short Bs[256 * 64];   // 32 KB
  const int t = threadIdx.x;
  const int lane = t & 63;
  const int w = t >> 6;
  const int wm = w >> 1, wn = w & 1;
  const int m0 = blockIdx.y * 128;
  const int n0 = blockIdx.x * 256;

  // staging: call c covers rows [c*32, c*32+32); lane row = c*32+w*8+(l>>3),
  // stored chunk l&7 holds global chunk (l&7)^(row&7).
  const int rowBase = w * 8 + (lane >> 3);
  const int gchunk = ((lane & 7) ^ ((lane >> 3) & 7)) * 8;  // ushort offset
  const size_t gA0 = (size_t)(m0 + rowBase) * 4096 + gchunk;
  const size_t gB0 = (size_t)(n0 + rowBase) * 4096 + gchunk;
  unsigned short* ldsA0 = As + w * 512;   // wave-uniform base (ushort units)
  unsigned short* ldsB0 = Bs + w * 512;

  const int am = lane & 15, quad = lane >> 4;
  int arow[4], brow[8];
#pragma unroll
  for (int i = 0; i < 4; ++i) arow[i] = (wm * 64 + i * 16 + am) * 64;
#pragma unroll
  for (int j = 0; j < 8; ++j) brow[j] = (wn * 128 + j * 16 + am) * 64;
  int swz[2];
#pragma unroll
  for (int h = 0; h < 2; ++h) swz[h] = (((h << 2) + quad) ^ (am & 7)) * 8;

  f32x4 acc[4][8];
#pragma unroll
  for (int i = 0; i < 4; ++i)
#pragma unroll
    for (int j = 0; j < 8; ++j) acc[i][j] = (f32x4){0.f, 0.f, 0.f, 0.f};

#pragma unroll 1
  for (int it = 0; it < 32; ++it) {
    const int kin = it * 64;
    __syncthreads();  // previous iteration's LDS reads complete
#pragma unroll
    for (int c = 0; c < 4; ++c)
      async_load16(X + gA0 + (size_t)c * (32 * 4096) + kin, ldsA0 + c * 2048);
#pragma unroll
    for (int c = 0; c < 8; ++c)
      async_load16(W + gB0 + (size_t)c * (32 * 4096) + kin, ldsB0 + c * 2048);
    __syncthreads();  // staging complete (drains vmcnt)

#pragma unroll
    for (int h = 0; h < 2; ++h) {
      f16x8 av[4], bv[8];
#pragma unroll
      for (int i = 0; i < 4; ++i) av[i] = *(const f16x8*)(As + arow[i] + swz[h]);
#pragma unroll
      for (int j = 0; j < 8; ++j) bv[j] = *(const f16x8*)(Bs + brow[j] + swz[h]);
#pragma unroll
      for (int mb = 0; mb < 4; ++mb)
#pragma unroll
        for (int nb = 0; nb < 8; ++nb)
          acc[mb][nb] = __builtin_amdgcn_mfma_f32_16x16x32_f16(
              av[mb], bv[nb], acc[mb][nb], 0, 0, 0);
    }
  }

  // epilogue: bias + per-group (64-col) min; wave covers 2 groups.
  float bv8[8];
#pragma unroll
  for (int nb = 0; nb < 8; ++nb) bv8[nb] = bias[n0 + wn * 128 + nb * 16 + am];
#pragma unroll
  for (int hh = 0; hh < 2; ++hh) {
    const int grp = (n0 >> 6) + wn * 2 + hh;
#pragma unroll
    for (int mb = 0; mb < 4; ++mb) {
#pragma unroll
      for (int reg = 0; reg < 4; ++reg) {
        float v = fminf(
            fminf(acc[mb][4 * hh + 0][reg] + bv8[4 * hh + 0],
                  acc[mb][4 * hh + 1][reg] + bv8[4 * hh + 1]),
            fminf(acc[mb][4 * hh + 2][reg] + bv8[4 * hh + 2],
                  acc[mb][4 * hh + 3][reg] + bv8[4 * hh + 3]));
        v = fminf(v, __shfl_xor(v, 1, 64));
        v = fminf(v, __shfl_xor(v, 2, 64));
        v = fminf(v, __shfl_xor(v, 4, 64));
        v = fminf(v, __shfl_xor(v, 8, 64));
        if (am == 0) {
          const int row = m0 + wm * 64 + mb * 16 + quad * 4 + reg;
          gmins[(size_t)row * 64 + grp] = v;
        }
      }
    }
  }
}

// ---- kernel 4: max over groups -> margin test ------------------------------
__global__ void finalize_margin(const float* __restrict__ gmins,
                                const float* __restrict__ rand_u,
                                float* __restrict__ out,
                                int* __restrict__ count, int* __restrict__ undec) {
  const int wv = threadIdx.x >> 6, lane = threadIdx.x & 63;
  const int row = blockIdx.x * 4 + wv;
  float v = gmins[(size_t)row * 64 + lane];
  v = fmaxf(v, __shfl_xor(v, 1, 64));
  v = fmaxf(v, __shfl_xor(v, 2, 64));
  v = fmaxf(v, __shfl_xor(v, 4, 64));
  v = fmaxf(v, __shfl_xor(v, 8, 64));
  v = fmaxf(v, __shfl_xor(v, 16, 64));
  v = fmaxf(v, __shfl_xor(v, 32, 64));
  if (lane == 0) {
    const float u = rand_u[row];
    const float slo = 1.0f / (1.0f + expf(-(v - MARGIN_EPS)));
    const float shi = 1.0f / (1.0f + expf(-(v + MARGIN_EPS)));
    if (u < slo) {
      out[row] = 1.0f;
    } else if (u >= shi) {
      out[row] = 0.0f;
    } else {
      const int i = atomicAdd(count, 1);
      if (i < 8192) undec[i] = row;
    }
  }
}

// ---- kernel 5: zero ybuf (96 slots x 4096 floats) --------------------------
__global__ void zero_ybuf(float4* __restrict__ p) {
  p[(size_t)blockIdx.x * 256 + threadIdx.x] = (float4){0.f, 0.f, 0.f, 0.f};
}

// ---- kernel 6: exact fp32 recompute, W read ONCE ---------------------------
// grid (64 groups, 4 k-chunks). Block stages its W chunk (64 cols x 512 k)
// reconstructed to fp32 in LDS (stride 513 -> conflict-free compute reads),
// then loops undecided slots, atomicAdd partial dot into ybuf[s][col].
__global__ __launch_bounds__(256) void recompute_rows(
    const unsigned short* __restrict__ X, const unsigned short* __restrict__ W,
    const int* __restrict__ count, const int* __restrict__ undec,
    float* __restrict__ ybuf) {
  __shared__ float wf[64 * 513];   // 131328 B
  __shared__ float part[256];
  const int g = blockIdx.x, kc = blockIdx.y;
  const int t = threadIdx.x;
  int n = *count;
  if (n > MAX_UNDEC) n = MAX_UNDEC;
  if (n == 0) return;

  {  // stage W chunk: thread t -> col t>>2, k-segment t&3 (128 k each)
    const int cl = t >> 2, ks = t & 3;
    const unsigned short* wp =
        W + (size_t)(g * 64 + cl) * 4096 + kc * 512 + ks * 128;
    float* dst = wf + cl * 513 + ks * 128;
    for (int i = 0; i < 128; i += 8) {
      uint4 hv = *(const uint4*)(wp + i);
      uint4 lv = *(const uint4*)(wp + 2048 + i);
      const unsigned* hw = (const unsigned*)&hv;
      const unsigned* lw = (const unsigned*)&lv;
#pragma unroll
      for (int m = 0; m < 4; ++m) {
        dst[i + 2 * m] = us2f((unsigned short)(hw[m] & 0xFFFF)) +
                         us2f((unsigned short)(lw[m] & 0xFFFF));
        dst[i + 2 * m + 1] = us2f((unsigned short)(hw[m] >> 16)) +
                             us2f((unsigned short)(lw[m] >> 16));
      }
    }
  }
  __syncthreads();

  const int col = t & 63, kq = t >> 6;
  const float* wcol = wf + col * 513 + kq * 128;
  for (int s = 0; s < n; ++s) {
    const int row = undec[s];
    const unsigned short* xp = X + (size_t)row * 4096 + kc * 512 + kq * 128;
    float acc = 0.f;
    for (int i = 0; i < 128; i += 8) {
      uint4 hv = *(const uint4*)(xp + i);
      uint4 lv = *(const uint4*)(xp + 2048 + i);
      const unsigned* hw = (const unsigned*)&hv;
      const unsigned* lw = (const unsigned*)&lv;
#pragma unroll
      for (int m = 0; m < 4; ++m) {
        const float x0 = us2f((unsigned short)(hw[m] & 0xFFFF)) +
                         us2f((unsigned short)(lw[m] & 0xFFFF));
        const float x1 = us2f((unsigned short)(hw[m] >> 16)) +
                         us2f((unsigned short)(lw[m] >> 16));
        acc = fmaf(x0, wcol[i + 2 * m], acc);
        acc = fmaf(x1, wcol[i + 2 * m + 1], acc);
      }
    }
    part[t] = acc;
    __syncthreads();
    if (t < 64) {
      const float y = part[t] + part[t + 64] + part[t + 128] + part[t + 192];
      atomicAdd(ybuf + (size_t)s * 4096 + g * 64 + t, y);
    }
    __syncthreads();
  }
}

// ---- kernel 7: final decision for undecided rows ---------------------------
__global__ void decide(const float* __restrict__ ybuf,
                       const int* __restrict__ undec, const int* __restrict__ count,
                       const float* __restrict__ bias,
                       const float* __restrict__ rand_u, float* __restrict__ out) {
  __shared__ float gm[64];
  int n = *count;
  if (n > MAX_UNDEC) n = MAX_UNDEC;
  const int s = blockIdx.x;
  if (s >= n) return;
  const int t = threadIdx.x;
  const int g = t >> 2, p4 = t & 3;
  const float* yb = ybuf + (size_t)s * 4096;
  const int c0 = g * 64 + p4 * 16;
  float m = 3.4e38f;
#pragma unroll
  for (int e = 0; e < 16; ++e) m = fminf(m, yb[c0 + e] + bias[c0 + e]);
  m = fminf(m, __shfl_xor(m, 1, 64));
  m = fminf(m, __shfl_xor(m, 2, 64));
  if (p4 == 0) gm[g] = m;
  __syncthreads();
  if (t < 64) {
    float v = gm[t];
    v = fmaxf(v, __shfl_xor(v, 1, 64));
    v = fmaxf(v, __shfl_xor(v, 2, 64));
    v = fmaxf(v, __shfl_xor(v, 4, 64));
    v = fmaxf(v, __shfl_xor(v, 8, 64));
    v = fmaxf(v, __shfl_xor(v, 16, 64));
    v = fmaxf(v, __shfl_xor(v, 32, 64));
    if (t == 0) {
      const int row = undec[s];
      const float sg = 1.0f / (1.0f + expf(-v));
      out[row] = (rand_u[row] < sg) ? 1.0f : 0.0f;
    }
  }
}

extern "C" void kernel_launch(void* const* d_in, const int* in_sizes, int n_in,
                              void* d_out, int out_size, void* d_ws, size_t ws_size,
                              hipStream_t stream) {
  float* x = (float*)d_in[0];           // [8192, 2048] fp32 (mutated in place)
  float* weight = (float*)d_in[1];      // [4096, 2048] fp32 (mutated in place)
  const float* bias = (const float*)d_in[2];
  const float* rand_u = (const float*)d_in[3];
  const int* montn = (const int*)d_in[4];
  float* out = (float*)d_out;

  char* ws = (char*)d_ws;
  unsigned* mask32 = (unsigned*)ws;              // 256 B
  int* count = (int*)(ws + 256);                 // 4 B
  int* undec = (int*)(ws + 512);                 // 32 KB
  float* ybuf = (float*)(ws + 65536);            // 96*4096*4 = 1.5 MB
  float* gmins = (float*)(ws + 65536 + 1572864); // 2 MB

  build_mask<<<1, 256, 0, stream>>>(montn, mask32, count);
  convert_split<<<3072, 256, 0, stream>>>(x, weight, mask32);
  gemm_minmax<<<dim3(16, 64), 256, 0, stream>>>(
      (const unsigned short*)x, (const unsigned short*)weight, bias, gmins);
  finalize_margin<<<2048, 256, 0, stream>>>(gmins, rand_u, out, count, undec);
  zero_ybuf<<<384, 256, 0, stream>>>((float4*)ybuf);
  recompute_rows<<<dim3(64, 4), 256, 0, stream>>>(
      (const unsigned short*)x, (const unsigned short*)weight, count, undec, ybuf);
  decide<<<MAX_UNDEC, 256, 0, stream>>>(ybuf, undec, count, bias, rand_u, out);
}